// Round 15
// baseline (319.976 us; speedup 1.0000x reference)
//
#include <hip/hip_runtime.h>
#include <hip/hip_bf16.h>
#include <stdint.h>

#define H_DIM 4096
#define NH 32
#define HD 128
#define SEQ 1024
#define CTX 4096
#define KVL (CTX + SEQ)      // 5120
#define W3H (3 * H_DIM)      // 12288
// 1/sqrt(128) * log2(e): softmax in exp2 domain (v_exp_f32 is natively 2^x)
#define QK_SCALE_LOG2E 0.12751743075305723f

typedef short short8 __attribute__((ext_vector_type(8)));
typedef float f32x4 __attribute__((ext_vector_type(4)));

// async global->LDS, 16B per lane; LDS dest must be wave-uniform base (HW adds lane*16)
#define GLOAD_LDS16(g, l)                                             \
  __builtin_amdgcn_global_load_lds(                                   \
      (const __attribute__((address_space(1))) void*)(g),             \
      (__attribute__((address_space(3))) void*)(l), 16, 0, 0)

__device__ __forceinline__ unsigned short f2b(float f) {
  union { float f; unsigned u; } v; v.f = f;
  return (unsigned short)((v.u + 0x7FFFu + ((v.u >> 16) & 1u)) >> 16);
}
__device__ __forceinline__ float b2f(unsigned short u) {
  union { unsigned u; float f; } v; v.u = ((unsigned)u) << 16;
  return v.f;
}

// ---------------- fused f32 -> bf16 convert for X and W ----------------
__global__ void k_cvt2(const float* __restrict__ X, const float* __restrict__ W,
                       unsigned short* __restrict__ Xb, unsigned short* __restrict__ Wb) {
  const int nx = SEQ * H_DIM / 4;
  const int nw = W3H * H_DIM / 4;
  int i = blockIdx.x * 256 + threadIdx.x;
  const float* s;
  unsigned short* d;
  int j;
  if (i < nx) { s = X; d = Xb; j = i; }
  else { j = i - nx; if (j >= nw) return; s = W; d = Wb; }
  float4 v = reinterpret_cast<const float4*>(s)[j];
  ushort4 o;
  o.x = f2b(v.x); o.y = f2b(v.y); o.z = f2b(v.z); o.w = f2b(v.w);
  reinterpret_cast<ushort4*>(d)[j] = o;
}

// ---------------- QKV GEMM v4: 256M x 192N, 256 blocks (1/CU), 8-phase ----------------
#define GBM 256
#define GBN 192
#define GBK 64
#define GNKT (H_DIM / GBK)   // 64
#define LBUF 57344           // 56KB per dbuf half
__global__ __launch_bounds__(512, 1) void k_gemm_qkv(
    const unsigned short* __restrict__ A,
    const unsigned short* __restrict__ B,
    unsigned short* __restrict__ C) {
  __shared__ __align__(16) char Lds[2 * LBUF];
  const int tid = threadIdx.x;
  const int lane = tid & 63;
  const int wid = tid >> 6;          // 0..7
  const int wm = wid >> 2;           // 0..1  (M half, 128 rows)
  const int wn = wid & 3;            // 0..3  (N quarter, 48 cols)
  const int lq = lane >> 4;          // 0..3
  const int lr = lane & 15;

  // XCD-bijective swizzle: 256 blocks = 8 XCDs x 32
  const int id = blockIdx.x;
  const int wg = (id & 7) * 32 + (id >> 3);
  const int bm = wg & 3;             // 4 M-tiles
  const int bn = wg >> 2;            // 64 N-tiles

  const unsigned short* Abase = A + (size_t)(bm * GBM) * H_DIM;
  const unsigned short* Bbase = B + (size_t)(bn * GBN) * H_DIM;
  const int sel = 8 * ((lane & 7) ^ (lane >> 3));
  const int srow = lane >> 3;

#define GA2(t, j0, b)                                                          \
  {                                                                            \
    _Pragma("unroll") for (int j = (j0); j < (j0) + 2; ++j) {                  \
      int c = wid + j * 8;                                                     \
      GLOAD_LDS16(Abase + (size_t)(c * 8 + srow) * H_DIM + (t) * GBK + sel,    \
                  Lds + (b) * LBUF + c * 1024);                                \
    }                                                                          \
  }
#define GB2(t, j0, b)                                                          \
  {                                                                            \
    _Pragma("unroll") for (int j = (j0); j < (j0) + 2; ++j) {                  \
      int c = wid + j * 8;                                                     \
      GLOAD_LDS16(Bbase + (size_t)(c * 8 + srow) * H_DIM + (t) * GBK + sel,    \
                  Lds + (b) * LBUF + 32768 + c * 1024);                        \
    }                                                                          \
  }
#define GB1(t, j0, b)                                                          \
  {                                                                            \
    int c = wid + (j0) * 8;                                                    \
    GLOAD_LDS16(Bbase + (size_t)(c * 8 + srow) * H_DIM + (t) * GBK + sel,      \
                Lds + (b) * LBUF + 32768 + c * 1024);                          \
  }

  f32x4 acc[8][3] = {};

#define GPHASE(T, q)                                                           \
  {                                                                            \
    const int cb_ = ((T) & 1) * LBUF;                                          \
    short8 af[2][2];                                                           \
    _Pragma("unroll") for (int mm = 0; mm < 2; ++mm)                           \
      _Pragma("unroll") for (int kk = 0; kk < 2; ++kk)                         \
        af[mm][kk] = *reinterpret_cast<const short8*>(                         \
            Lds + cb_ + (wm * 128 + ((q) * 2 + mm) * 16 + lr) * 128 +          \
            16 * ((kk * 4 + lq) ^ (lr & 7)));                                  \
    if ((q) == 0) {                                                            \
      _Pragma("unroll") for (int n = 0; n < 3; ++n)                            \
        _Pragma("unroll") for (int kk = 0; kk < 2; ++kk)                       \
          bfr[n][kk] = *reinterpret_cast<const short8*>(                       \
              Lds + cb_ + 32768 + (wn * 48 + n * 16 + lr) * 128 +              \
              16 * ((kk * 4 + lq) ^ (lr & 7)));                                \
    }                                                                          \
    if ((q) == 0 && (T) + 1 < GNKT) GA2((T) + 1, 0, ((T) + 1) & 1);            \
    if ((q) == 1 && (T) + 1 < GNKT) GA2((T) + 1, 2, ((T) + 1) & 1);            \
    if ((q) == 2 && (T) + 2 < GNKT) GB2((T) + 2, 0, (T) & 1);                  \
    if ((q) == 3 && (T) + 2 < GNKT) GB1((T) + 2, 2, (T) & 1);                  \
    if ((q) == 3) {                                                            \
      if ((T) + 2 < GNKT) {                                                    \
        asm volatile("s_waitcnt vmcnt(3)" ::: "memory");                       \
      } else {                                                                 \
        asm volatile("s_waitcnt vmcnt(0)" ::: "memory");                       \
      }                                                                        \
    }                                                                          \
    __builtin_amdgcn_sched_barrier(0);                                         \
    __builtin_amdgcn_s_barrier();                                              \
    asm volatile("s_waitcnt lgkmcnt(0)" ::: "memory");                         \
    __builtin_amdgcn_sched_barrier(0);                                         \
    __builtin_amdgcn_s_setprio(1);                                             \
    _Pragma("unroll") for (int kk = 0; kk < 2; ++kk)                           \
      _Pragma("unroll") for (int mm = 0; mm < 2; ++mm)                         \
        _Pragma("unroll") for (int n = 0; n < 3; ++n)                          \
          acc[(q) * 2 + mm][n] = __builtin_amdgcn_mfma_f32_16x16x32_bf16(      \
              af[mm][kk], bfr[n][kk], acc[(q) * 2 + mm][n], 0, 0, 0);          \
    __builtin_amdgcn_s_setprio(0);                                             \
    __builtin_amdgcn_sched_barrier(0);                                         \
    __builtin_amdgcn_s_barrier();                                              \
    __builtin_amdgcn_sched_barrier(0);                                         \
  }

  GA2(0, 0, 0);
  GA2(0, 2, 0);
  GB2(0, 0, 0);
  GB1(0, 2, 0);
  GB2(1, 0, 1);
  GB1(1, 2, 1);
  asm volatile("s_waitcnt vmcnt(3)" ::: "memory");
  __builtin_amdgcn_sched_barrier(0);
  __builtin_amdgcn_s_barrier();
  __builtin_amdgcn_sched_barrier(0);

  for (int T = 0; T < GNKT; ++T) {
    short8 bfr[3][2];
    GPHASE(T, 0);
    GPHASE(T, 1);
    GPHASE(T, 2);
    GPHASE(T, 3);
  }

  const int r0 = bm * GBM + wm * 128 + lq * 4;
  const int c0 = bn * GBN + wn * 48 + lr;
#pragma unroll
  for (int m = 0; m < 8; ++m)
#pragma unroll
    for (int n = 0; n < 3; ++n)
#pragma unroll
      for (int r = 0; r < 4; ++r)
        C[(size_t)(r0 + m * 16 + r) * W3H + c0 + n * 16] = f2b(acc[m][n][r]);
#undef GA2
#undef GB2
#undef GB1
#undef GPHASE
}

// ---------------- build Kb[h][kv][d] bf16 ----------------
__global__ void k_build_k(const float* __restrict__ cK, const unsigned short* __restrict__ QKV,
                          unsigned short* __restrict__ Kb) {
  int idx = (blockIdx.x * 256 + threadIdx.x) * 4;
  if (idx >= NH * KVL * HD) return;
  int h = idx / (KVL * HD);
  int rem = idx % (KVL * HD);
  int kv = rem / HD;
  int d = rem % HD;
  ushort4 o;
  if (kv < CTX) {
    float4 v = *reinterpret_cast<const float4*>(cK + ((size_t)kv * NH + h) * HD + d);
    o.x = f2b(v.x); o.y = f2b(v.y); o.z = f2b(v.z); o.w = f2b(v.w);
  } else {
    o = *reinterpret_cast<const ushort4*>(QKV + (size_t)(kv - CTX) * W3H + H_DIM + h * HD + d);
  }
  *reinterpret_cast<ushort4*>(Kb + idx) = o;
}

// ---------------- build Vt[h][d][kv] bf16 (transposed) ----------------
__global__ void k_build_vt(const float* __restrict__ cV, const unsigned short* __restrict__ QKV,
                           unsigned short* __restrict__ Vt) {
  __shared__ unsigned short T[HD][66];
  const int h = blockIdx.y;
  const int kt = blockIdx.x;
  const int t = threadIdx.x;
#pragma unroll
  for (int e = 0; e < 8; ++e) {
    int idx = (t + e * 256) * 4;
    int kvl = idx >> 7;
    int d = idx & 127;
    int kv = kt * 64 + kvl;
    unsigned short a, b, c, w;
    if (kv < CTX) {
      float4 v = *reinterpret_cast<const float4*>(cV + ((size_t)kv * NH + h) * HD + d);
      a = f2b(v.x); b = f2b(v.y); c = f2b(v.z); w = f2b(v.w);
    } else {
      ushort4 u = *reinterpret_cast<const ushort4*>(QKV + (size_t)(kv - CTX) * W3H + 2 * H_DIM + h * HD + d);
      a = u.x; b = u.y; c = u.z; w = u.w;
    }
    T[d][kvl] = a; T[d + 1][kvl] = b; T[d + 2][kvl] = c; T[d + 3][kvl] = w;
  }
  __syncthreads();
#pragma unroll
  for (int e = 0; e < 8; ++e) {
    int idx = (t + e * 256) * 4;
    int d = idx >> 6;
    int kv0 = idx & 63;
    ushort4 o;
    o.x = T[d][kv0]; o.y = T[d][kv0 + 1]; o.z = T[d][kv0 + 2]; o.w = T[d][kv0 + 3];
    *reinterpret_cast<ushort4*>(Vt + ((size_t)h * HD + d) * KVL + kt * 64 + kv0) = o;
  }
}

// ---------------- flash attention v8: v7 + exp2-domain softmax ----------------
// Q pre-scaled by 1/sqrt(d)*log2(e); P = exp2f(S - m) (compiler emits v_exp_f32
// directly, no asm pinning -> no spill). m/l/Mp in log2 domain; combine matches.
// Defer-max THR=8 bounds P by 2^8. All else identical to R14's v7.
#define PKV(x) ((((x) & 32)) | (((x) & 12) << 1) | (((x) & 16) >> 2) | ((x) & 3))
#define KVT 64
#define NT (KVL / KVT)   // 80
#define NT2 (NT / 2)     // 40 per split
__global__ __launch_bounds__(256, 2) void k_attn(
    const unsigned short* __restrict__ QKV,
    const unsigned short* __restrict__ Kb,
    const unsigned short* __restrict__ Vt,
    float* __restrict__ A0,      // split-0 unnormalized partial [SEQ][H_DIM]
    float* __restrict__ A1,      // split-1 unnormalized partial
    float* __restrict__ Mp,      // [2][NH][SEQ] running max (log2 domain)
    float* __restrict__ Lp) {    // [2][NH][SEQ] running sum
  __shared__ unsigned short Ks[2][KVT * HD];  // 2x16KB, swizzled, row-permuted
  __shared__ unsigned short Vs[2][KVT * HD];  // 2x16KB, swizzled
  const int tid = threadIdx.x, lane = tid & 63, wid = tid >> 6;
  const int g = lane >> 4;    // lane quarter
  const int qi = lane & 15;   // q within 16-row half
  const int id = blockIdx.x;
  const int xcd = id & 7, slot = id >> 3;       // slot 0..63
  const int h = xcd * 4 + (slot >> 4);
  const int rem = slot & 15;
  const int qt = rem >> 1;                      // 0..7 (128-q tiles)
  const int split = rem & 1;
  const int kt0 = split * NT2;
  const int q0 = qt * 128 + wid * 32;

  // Q fragments (B-operand) for both halves, pre-scaled by 1/sqrt(d)*log2(e)
  short8 qf[2][4];
#pragma unroll
  for (int hf = 0; hf < 2; ++hf)
#pragma unroll
    for (int c = 0; c < 4; ++c) {
      short8 q = *reinterpret_cast<const short8*>(
          QKV + (size_t)(q0 + hf * 16 + qi) * W3H + h * HD + c * 32 + g * 8);
      short8 t;
#pragma unroll
      for (int j = 0; j < 8; ++j) t[j] = (short)f2b(b2f((unsigned short)q[j]) * QK_SCALE_LOG2E);
      qf[hf][c] = t;
    }

  float m_r[2] = {-1e30f, -1e30f}, l_r[2] = {0.f, 0.f};
  f32x4 acc_o[2][8] = {};   // [half][nd]: rows d=nd*16+g*4+r, col q

  const char* Kh = (const char*)(Kb + (size_t)h * KVL * HD);
  const char* Vh = (const char*)(Vt + (size_t)h * HD * KVL);

#define STAGE_K(t, b)                                                          \
  {                                                                            \
    _Pragma("unroll") for (int i = 0; i < 4; ++i) {                            \
      int c = wid * 4 + i;                                                     \
      int krow = c * 4 + (lane >> 4);          /* LDS row */                   \
      int kglob = PKV(krow);                   /* permuted global kv row */    \
      int klcb = (16 * (lane & 15)) ^ ((krow & 7) << 4);                       \
      GLOAD_LDS16(Kh + (size_t)((t) * KVT + kglob) * 256 + klcb,               \
                  (char*)Ks[b] + c * 1024);                                    \
    }                                                                          \
  }
#define STAGE_V(t, b)                                                          \
  {                                                                            \
    _Pragma("unroll") for (int i = 0; i < 4; ++i) {                            \
      int c = wid * 4 + i;                                                     \
      int vrow = c * 8 + (lane >> 3);                                          \
      int vlcb = (16 * (lane & 7)) ^ ((vrow & 7) << 4);                        \
      GLOAD_LDS16(Vh + (size_t)vrow * (KVL * 2) + (size_t)(t) * 128 + vlcb,    \
                  (char*)Vs[b] + c * 1024);                                    \
    }                                                                          \
  }

  STAGE_K(kt0, 0);
  STAGE_V(kt0, 0);
  STAGE_K(kt0 + 1, 1);
  STAGE_V(kt0 + 1, 1);
  __syncthreads();   // drains all 4 staging DMAs; tiles 0,1 visible

  for (int kt = 0; kt < NT2; ++kt) {
    const int cur = kt & 1;

    // ---- S^T = K Q^T on tile kt (buf cur) ----
    f32x4 s[2][4];
#pragma unroll
    for (int n = 0; n < 4; ++n) {
      s[0][n] = (f32x4){0.f, 0.f, 0.f, 0.f};
      s[1][n] = (f32x4){0.f, 0.f, 0.f, 0.f};
    }
    __builtin_amdgcn_s_setprio(1);
#pragma unroll
    for (int n = 0; n < 4; ++n) {
      int row = n * 16 + qi;
#pragma unroll
      for (int c = 0; c < 4; ++c) {
        int cb = (c * 32 + g * 8) * 2;
        short8 kf = *reinterpret_cast<const short8*>(
            (const char*)Ks[cur] + row * 256 + (cb ^ ((row & 7) << 4)));
        s[0][n] = __builtin_amdgcn_mfma_f32_16x16x32_bf16(kf, qf[0][c], s[0][n], 0, 0, 0);
        s[1][n] = __builtin_amdgcn_mfma_f32_16x16x32_bf16(kf, qf[1][c], s[1][n], 0, 0, 0);
      }
    }
    __builtin_amdgcn_s_setprio(0);

    // ---- online softmax in exp2 domain (defer-max THR=8); l lane-local ----
    float p[2][4][4];
    int okv = 1;
    float tmax[2];
#pragma unroll
    for (int hf = 0; hf < 2; ++hf) {
      float t0 = s[hf][0][0];
#pragma unroll
      for (int n = 0; n < 4; ++n)
#pragma unroll
        for (int r = 0; r < 4; ++r) t0 = fmaxf(t0, s[hf][n][r]);
      t0 = fmaxf(t0, __shfl_xor(t0, 16, 64));
      t0 = fmaxf(t0, __shfl_xor(t0, 32, 64));
      tmax[hf] = t0;
      okv &= (t0 <= m_r[hf] + 8.0f);
    }
    if (!__all(okv)) {
#pragma unroll
      for (int hf = 0; hf < 2; ++hf) {
        float mn = fmaxf(m_r[hf], tmax[hf]);
        float alpha = exp2f(m_r[hf] - mn);
        l_r[hf] *= alpha;
        m_r[hf] = mn;
#pragma unroll
        for (int nd = 0; nd < 8; ++nd) acc_o[hf][nd] *= alpha;
      }
    }
#pragma unroll
    for (int hf = 0; hf < 2; ++hf) {
      float sum = 0.f;
#pragma unroll
      for (int n = 0; n < 4; ++n)
#pragma unroll
        for (int r = 0; r < 4; ++r) {
          p[hf][n][r] = exp2f(s[hf][n][r] - m_r[hf]);
          sum += p[hf][n][r];
        }
      l_r[hf] += sum;
    }

    // ---- pack to bf16 pairs; PV fragments = register renames (PKV ordering) ----
    unsigned pr[2][4][2];
#pragma unroll
    for (int hf = 0; hf < 2; ++hf)
#pragma unroll
      for (int n = 0; n < 4; ++n)
#pragma unroll
        for (int rr = 0; rr < 2; ++rr) {
          union { __hip_bfloat162 b; unsigned u; } cv;
          cv.b = __float22bfloat162_rn(make_float2(p[hf][n][2 * rr], p[hf][n][2 * rr + 1]));
          pr[hf][n][rr] = cv.u;
        }
#pragma unroll
    for (int kc = 0; kc < 2; ++kc) {
      short8 pv[2];
#pragma unroll
      for (int hf = 0; hf < 2; ++hf) {
        union { unsigned u[4]; short8 s8; } u;
        u.u[0] = pr[hf][2 * kc][0];
        u.u[1] = pr[hf][2 * kc][1];
        u.u[2] = pr[hf][2 * kc + 1][0];
        u.u[3] = pr[hf][2 * kc + 1][1];
        pv[hf] = u.s8;
      }
      __builtin_amdgcn_s_setprio(1);
#pragma unroll
      for (int nd = 0; nd < 8; ++nd) {
        int row = nd * 16 + qi;
        int cb = kc * 64 + g * 16;
        short8 vf = *reinterpret_cast<const short8*>(
            (const char*)Vs[cur] + row * 128 + (cb ^ ((row & 7) << 4)));
        acc_o[0][nd] = __builtin_amdgcn_mfma_f32_16x16x32_bf16(vf, pv[0], acc_o[0][nd], 0, 0, 0);
        acc_o[1][nd] = __builtin_amdgcn_mfma_f32_16x16x32_bf16(vf, pv[1], acc_o[1][nd], 0, 0, 0);
      }
      __builtin_amdgcn_s_setprio(0);
    }

    __syncthreads();   // all waves done with tile kt; iter kt-1's staged DMAs drained
    if (kt + 2 < NT2) {
      STAGE_K(kt0 + kt + 2, cur);   // buf cur free; lands by next iter's barrier
      STAGE_V(kt0 + kt + 2, cur);
    }
  }

  // cross-quarter l reduction (deferred from the loop)
#pragma unroll
  for (int hf = 0; hf < 2; ++hf) {
    l_r[hf] += __shfl_xor(l_r[hf], 16, 64);
    l_r[hf] += __shfl_xor(l_r[hf], 32, 64);
  }

  float* Op = split ? A1 : A0;
#pragma unroll
  for (int hf = 0; hf < 2; ++hf) {
    float* orow = Op + (size_t)(q0 + hf * 16 + qi) * H_DIM + h * HD;
#pragma unroll
    for (int nd = 0; nd < 8; ++nd)
      *reinterpret_cast<float4*>(orow + nd * 16 + g * 4) =
          *reinterpret_cast<const float4*>(&acc_o[hf][nd]);
    if (g == 0) {
      int q = q0 + hf * 16 + qi;
      Mp[split * (NH * SEQ) + h * SEQ + q] = m_r[hf];
      Lp[split * (NH * SEQ) + h * SEQ + q] = l_r[hf];
    }
  }
#undef STAGE_K
#undef STAGE_V
}

// ---------------- combine the two KV-splits (m in log2 domain) ----------------
__global__ void k_combine(const float* __restrict__ A1, const float* __restrict__ Mp,
                          const float* __restrict__ Lp, float* __restrict__ out) {
  int i4 = blockIdx.x * 256 + threadIdx.x;  // < SEQ*H_DIM/4
  int q = i4 >> 10;                          // H_DIM/4 = 1024 float4 per row
  int c4 = i4 & 1023;
  int h = c4 >> 5;                           // 32 float4 per head
  float m0 = Mp[h * SEQ + q], m1 = Mp[NH * SEQ + h * SEQ + q];
  float l0 = Lp[h * SEQ + q], l1 = Lp[NH * SEQ + h * SEQ + q];
  float M = fmaxf(m0, m1);
  float w0 = exp2f(m0 - M), w1 = exp2f(m1 - M);
  float inv = 1.0f / (w0 * l0 + w1 * l1);
  float4 a0 = reinterpret_cast<const float4*>(out)[i4];
  float4 a1 = reinterpret_cast<const float4*>(A1)[i4];
  float4 o;
  o.x = (w0 * a0.x + w1 * a1.x) * inv;
  o.y = (w0 * a0.y + w1 * a1.y) * inv;
  o.z = (w0 * a0.z + w1 * a1.z) * inv;
  o.w = (w0 * a0.w + w1 * a1.w) * inv;
  reinterpret_cast<float4*>(out)[i4] = o;
}

extern "C" void kernel_launch(void* const* d_in, const int* in_sizes, int n_in,
                              void* d_out, int out_size, void* d_ws, size_t ws_size,
                              hipStream_t stream) {
  const float* X = (const float*)d_in[0];
  const float* W = (const float*)d_in[1];
  const float* cK = (const float*)d_in[2];
  const float* cV = (const float*)d_in[3];
  float* out = (float*)d_out;
  char* ws = (char*)d_ws;

  // ws: Xb[0,8M) QKVb[8M,32M) Wb/Kb[32M,72M) Vt[72M,112M) A1[112M,128M)
  // Mp/Lp alias Xb's first 512K — Xb is dead after the GEMM, k_attn runs after it,
  // and k_cvt2 fully rewrites Xb every call => deterministic across replays.
  unsigned short* Xb = (unsigned short*)(ws);
  float* Mp = (float*)(ws);
  float* Lp = (float*)(ws + (256 << 10));
  unsigned short* QKVb = (unsigned short*)(ws + ((size_t)8 << 20));
  unsigned short* Wb = (unsigned short*)(ws + ((size_t)32 << 20));
  unsigned short* Kb = (unsigned short*)(ws + ((size_t)32 << 20));
  unsigned short* Vt = (unsigned short*)(ws + ((size_t)72 << 20));
  float* A1 = (float*)(ws + ((size_t)112 << 20));

  int ncvt = (SEQ * H_DIM + W3H * H_DIM) / 4;
  k_cvt2<<<(ncvt + 255) / 256, 256, 0, stream>>>(X, W, Xb, Wb);

  k_gemm_qkv<<<(SEQ / GBM) * (W3H / GBN), 512, 0, stream>>>(Xb, Wb, QKVb);

  k_build_k<<<(NH * KVL * HD / 4) / 256, 256, 0, stream>>>(cK, QKVb, Kb);
  dim3 gv(KVL / 64, NH);
  k_build_vt<<<gv, 256, 0, stream>>>(cV, QKVb, Vt);

  k_attn<<<SEQ / 128 * NH * 2, 256, 0, stream>>>(QKVb, Kb, Vt, out, A1, Mp, Lp);
  k_combine<<<(SEQ * H_DIM / 4) / 256, 256, 0, stream>>>(A1, Mp, Lp, out);
}

// Round 16
// 299.688 us; speedup vs baseline: 1.0677x; 1.0677x over previous
//
#include <hip/hip_runtime.h>
#include <hip/hip_bf16.h>
#include <stdint.h>

#define H_DIM 4096
#define NH 32
#define HD 128
#define SEQ 1024
#define CTX 4096
#define KVL (CTX + SEQ)      // 5120
#define W3H (3 * H_DIM)      // 12288
// 1/sqrt(128) * log2(e): softmax in log2 domain
#define QK_SCALE_LOG2E 0.12751743075305723f

#if __has_builtin(__builtin_amdgcn_exp2f)
#define FEXP2(x) __builtin_amdgcn_exp2f(x)
#else
#define FEXP2(x) __expf((x) * 0.6931471805599453f)
#endif

typedef short short8 __attribute__((ext_vector_type(8)));
typedef float f32x4 __attribute__((ext_vector_type(4)));

// async global->LDS, 16B per lane; LDS dest must be wave-uniform base (HW adds lane*16)
#define GLOAD_LDS16(g, l)                                             \
  __builtin_amdgcn_global_load_lds(                                   \
      (const __attribute__((address_space(1))) void*)(g),             \
      (__attribute__((address_space(3))) void*)(l), 16, 0, 0)

__device__ __forceinline__ unsigned short f2b(float f) {
  union { float f; unsigned u; } v; v.f = f;
  return (unsigned short)((v.u + 0x7FFFu + ((v.u >> 16) & 1u)) >> 16);
}
__device__ __forceinline__ float b2f(unsigned short u) {
  union { unsigned u; float f; } v; v.u = ((unsigned)u) << 16;
  return v.f;
}

// ---------------- fused f32 -> bf16 convert for X and W ----------------
__global__ void k_cvt2(const float* __restrict__ X, const float* __restrict__ W,
                       unsigned short* __restrict__ Xb, unsigned short* __restrict__ Wb) {
  const int nx = SEQ * H_DIM / 4;
  const int nw = W3H * H_DIM / 4;
  int i = blockIdx.x * 256 + threadIdx.x;
  const float* s;
  unsigned short* d;
  int j;
  if (i < nx) { s = X; d = Xb; j = i; }
  else { j = i - nx; if (j >= nw) return; s = W; d = Wb; }
  float4 v = reinterpret_cast<const float4*>(s)[j];
  ushort4 o;
  o.x = f2b(v.x); o.y = f2b(v.y); o.z = f2b(v.z); o.w = f2b(v.w);
  reinterpret_cast<ushort4*>(d)[j] = o;
}

// ---------------- QKV GEMM v4: 256M x 192N, 256 blocks (1/CU), 8-phase ----------------
#define GBM 256
#define GBN 192
#define GBK 64
#define GNKT (H_DIM / GBK)   // 64
#define LBUF 57344           // 56KB per dbuf half
__global__ __launch_bounds__(512, 1) void k_gemm_qkv(
    const unsigned short* __restrict__ A,
    const unsigned short* __restrict__ B,
    unsigned short* __restrict__ C) {
  __shared__ __align__(16) char Lds[2 * LBUF];
  const int tid = threadIdx.x;
  const int lane = tid & 63;
  const int wid = tid >> 6;          // 0..7
  const int wm = wid >> 2;           // 0..1  (M half, 128 rows)
  const int wn = wid & 3;            // 0..3  (N quarter, 48 cols)
  const int lq = lane >> 4;          // 0..3
  const int lr = lane & 15;

  // XCD-bijective swizzle: 256 blocks = 8 XCDs x 32
  const int id = blockIdx.x;
  const int wg = (id & 7) * 32 + (id >> 3);
  const int bm = wg & 3;             // 4 M-tiles
  const int bn = wg >> 2;            // 64 N-tiles

  const unsigned short* Abase = A + (size_t)(bm * GBM) * H_DIM;
  const unsigned short* Bbase = B + (size_t)(bn * GBN) * H_DIM;
  const int sel = 8 * ((lane & 7) ^ (lane >> 3));
  const int srow = lane >> 3;

#define GA2(t, j0, b)                                                          \
  {                                                                            \
    _Pragma("unroll") for (int j = (j0); j < (j0) + 2; ++j) {                  \
      int c = wid + j * 8;                                                     \
      GLOAD_LDS16(Abase + (size_t)(c * 8 + srow) * H_DIM + (t) * GBK + sel,    \
                  Lds + (b) * LBUF + c * 1024);                                \
    }                                                                          \
  }
#define GB2(t, j0, b)                                                          \
  {                                                                            \
    _Pragma("unroll") for (int j = (j0); j < (j0) + 2; ++j) {                  \
      int c = wid + j * 8;                                                     \
      GLOAD_LDS16(Bbase + (size_t)(c * 8 + srow) * H_DIM + (t) * GBK + sel,    \
                  Lds + (b) * LBUF + 32768 + c * 1024);                        \
    }                                                                          \
  }
#define GB1(t, j0, b)                                                          \
  {                                                                            \
    int c = wid + (j0) * 8;                                                    \
    GLOAD_LDS16(Bbase + (size_t)(c * 8 + srow) * H_DIM + (t) * GBK + sel,      \
                Lds + (b) * LBUF + 32768 + c * 1024);                          \
  }

  f32x4 acc[8][3] = {};

#define GPHASE(T, q)                                                           \
  {                                                                            \
    const int cb_ = ((T) & 1) * LBUF;                                          \
    short8 af[2][2];                                                           \
    _Pragma("unroll") for (int mm = 0; mm < 2; ++mm)                           \
      _Pragma("unroll") for (int kk = 0; kk < 2; ++kk)                         \
        af[mm][kk] = *reinterpret_cast<const short8*>(                         \
            Lds + cb_ + (wm * 128 + ((q) * 2 + mm) * 16 + lr) * 128 +          \
            16 * ((kk * 4 + lq) ^ (lr & 7)));                                  \
    if ((q) == 0) {                                                            \
      _Pragma("unroll") for (int n = 0; n < 3; ++n)                            \
        _Pragma("unroll") for (int kk = 0; kk < 2; ++kk)                       \
          bfr[n][kk] = *reinterpret_cast<const short8*>(                       \
              Lds + cb_ + 32768 + (wn * 48 + n * 16 + lr) * 128 +              \
              16 * ((kk * 4 + lq) ^ (lr & 7)));                                \
    }                                                                          \
    if ((q) == 0 && (T) + 1 < GNKT) GA2((T) + 1, 0, ((T) + 1) & 1);            \
    if ((q) == 1 && (T) + 1 < GNKT) GA2((T) + 1, 2, ((T) + 1) & 1);            \
    if ((q) == 2 && (T) + 2 < GNKT) GB2((T) + 2, 0, (T) & 1);                  \
    if ((q) == 3 && (T) + 2 < GNKT) GB1((T) + 2, 2, (T) & 1);                  \
    if ((q) == 3) {                                                            \
      if ((T) + 2 < GNKT) {                                                    \
        asm volatile("s_waitcnt vmcnt(3)" ::: "memory");                       \
      } else {                                                                 \
        asm volatile("s_waitcnt vmcnt(0)" ::: "memory");                       \
      }                                                                        \
    }                                                                          \
    __builtin_amdgcn_sched_barrier(0);                                         \
    __builtin_amdgcn_s_barrier();                                              \
    asm volatile("s_waitcnt lgkmcnt(0)" ::: "memory");                         \
    __builtin_amdgcn_sched_barrier(0);                                         \
    __builtin_amdgcn_s_setprio(1);                                             \
    _Pragma("unroll") for (int kk = 0; kk < 2; ++kk)                           \
      _Pragma("unroll") for (int mm = 0; mm < 2; ++mm)                         \
        _Pragma("unroll") for (int n = 0; n < 3; ++n)                          \
          acc[(q) * 2 + mm][n] = __builtin_amdgcn_mfma_f32_16x16x32_bf16(      \
              af[mm][kk], bfr[n][kk], acc[(q) * 2 + mm][n], 0, 0, 0);          \
    __builtin_amdgcn_s_setprio(0);                                             \
    __builtin_amdgcn_sched_barrier(0);                                         \
    __builtin_amdgcn_s_barrier();                                              \
    __builtin_amdgcn_sched_barrier(0);                                         \
  }

  GA2(0, 0, 0);
  GA2(0, 2, 0);
  GB2(0, 0, 0);
  GB1(0, 2, 0);
  GB2(1, 0, 1);
  GB1(1, 2, 1);
  asm volatile("s_waitcnt vmcnt(3)" ::: "memory");
  __builtin_amdgcn_sched_barrier(0);
  __builtin_amdgcn_s_barrier();
  __builtin_amdgcn_sched_barrier(0);

  for (int T = 0; T < GNKT; ++T) {
    short8 bfr[3][2];
    GPHASE(T, 0);
    GPHASE(T, 1);
    GPHASE(T, 2);
    GPHASE(T, 3);
  }

  const int r0 = bm * GBM + wm * 128 + lq * 4;
  const int c0 = bn * GBN + wn * 48 + lr;
#pragma unroll
  for (int m = 0; m < 8; ++m)
#pragma unroll
    for (int n = 0; n < 3; ++n)
#pragma unroll
      for (int r = 0; r < 4; ++r)
        C[(size_t)(r0 + m * 16 + r) * W3H + c0 + n * 16] = f2b(acc[m][n][r]);
#undef GA2
#undef GB2
#undef GB1
#undef GPHASE
}

// ---------------- build Kb[h][kv][d] bf16 ----------------
__global__ void k_build_k(const float* __restrict__ cK, const unsigned short* __restrict__ QKV,
                          unsigned short* __restrict__ Kb) {
  int idx = (blockIdx.x * 256 + threadIdx.x) * 4;
  if (idx >= NH * KVL * HD) return;
  int h = idx / (KVL * HD);
  int rem = idx % (KVL * HD);
  int kv = rem / HD;
  int d = rem % HD;
  ushort4 o;
  if (kv < CTX) {
    float4 v = *reinterpret_cast<const float4*>(cK + ((size_t)kv * NH + h) * HD + d);
    o.x = f2b(v.x); o.y = f2b(v.y); o.z = f2b(v.z); o.w = f2b(v.w);
  } else {
    o = *reinterpret_cast<const ushort4*>(QKV + (size_t)(kv - CTX) * W3H + H_DIM + h * HD + d);
  }
  *reinterpret_cast<ushort4*>(Kb + idx) = o;
}

// ---------------- build Vt[h][d][kv] bf16 (transposed) ----------------
__global__ void k_build_vt(const float* __restrict__ cV, const unsigned short* __restrict__ QKV,
                           unsigned short* __restrict__ Vt) {
  __shared__ unsigned short T[HD][66];
  const int h = blockIdx.y;
  const int kt = blockIdx.x;
  const int t = threadIdx.x;
#pragma unroll
  for (int e = 0; e < 8; ++e) {
    int idx = (t + e * 256) * 4;
    int kvl = idx >> 7;
    int d = idx & 127;
    int kv = kt * 64 + kvl;
    unsigned short a, b, c, w;
    if (kv < CTX) {
      float4 v = *reinterpret_cast<const float4*>(cV + ((size_t)kv * NH + h) * HD + d);
      a = f2b(v.x); b = f2b(v.y); c = f2b(v.z); w = f2b(v.w);
    } else {
      ushort4 u = *reinterpret_cast<const ushort4*>(QKV + (size_t)(kv - CTX) * W3H + 2 * H_DIM + h * HD + d);
      a = u.x; b = u.y; c = u.z; w = u.w;
    }
    T[d][kvl] = a; T[d + 1][kvl] = b; T[d + 2][kvl] = c; T[d + 3][kvl] = w;
  }
  __syncthreads();
#pragma unroll
  for (int e = 0; e < 8; ++e) {
    int idx = (t + e * 256) * 4;
    int d = idx >> 6;
    int kv0 = idx & 63;
    ushort4 o;
    o.x = T[d][kv0]; o.y = T[d][kv0 + 1]; o.z = T[d][kv0 + 2]; o.w = T[d][kv0 + 3];
    *reinterpret_cast<ushort4*>(Vt + ((size_t)h * HD + d) * KVL + kt * 64 + kv0) = o;
  }
}

// ---------------- flash attention v9: R14's v7 + native-exp2 log2-domain softmax ----------------
// Identical structure to R14 (single-S, PKV zero-shuffle PV, defer-max, deferred l).
// Only change: softmax in log2 domain via FEXP2 = __builtin_amdgcn_exp2f (bare
// v_exp_f32, schedulable, no libcall fixups, no asm pinning). Q pre-scale carries
// log2(e); m/l/Mp/combine consistently log2-domain.
#define PKV(x) ((((x) & 32)) | (((x) & 12) << 1) | (((x) & 16) >> 2) | ((x) & 3))
#define KVT 64
#define NT (KVL / KVT)   // 80
#define NT2 (NT / 2)     // 40 per split
__global__ __launch_bounds__(256, 2) void k_attn(
    const unsigned short* __restrict__ QKV,
    const unsigned short* __restrict__ Kb,
    const unsigned short* __restrict__ Vt,
    float* __restrict__ A0,      // split-0 unnormalized partial [SEQ][H_DIM]
    float* __restrict__ A1,      // split-1 unnormalized partial
    float* __restrict__ Mp,      // [2][NH][SEQ] running max (log2 domain)
    float* __restrict__ Lp) {    // [2][NH][SEQ] running sum
  __shared__ unsigned short Ks[2][KVT * HD];  // 2x16KB, swizzled, row-permuted
  __shared__ unsigned short Vs[2][KVT * HD];  // 2x16KB, swizzled
  const int tid = threadIdx.x, lane = tid & 63, wid = tid >> 6;
  const int g = lane >> 4;    // lane quarter
  const int qi = lane & 15;   // q within 16-row half
  const int id = blockIdx.x;
  const int xcd = id & 7, slot = id >> 3;       // slot 0..63
  const int h = xcd * 4 + (slot >> 4);
  const int rem = slot & 15;
  const int qt = rem >> 1;                      // 0..7 (128-q tiles)
  const int split = rem & 1;
  const int kt0 = split * NT2;
  const int q0 = qt * 128 + wid * 32;

  // Q fragments (B-operand) for both halves, pre-scaled by 1/sqrt(d)*log2(e)
  short8 qf[2][4];
#pragma unroll
  for (int hf = 0; hf < 2; ++hf)
#pragma unroll
    for (int c = 0; c < 4; ++c) {
      short8 q = *reinterpret_cast<const short8*>(
          QKV + (size_t)(q0 + hf * 16 + qi) * W3H + h * HD + c * 32 + g * 8);
      short8 t;
#pragma unroll
      for (int j = 0; j < 8; ++j) t[j] = (short)f2b(b2f((unsigned short)q[j]) * QK_SCALE_LOG2E);
      qf[hf][c] = t;
    }

  float m_r[2] = {-1e30f, -1e30f}, l_r[2] = {0.f, 0.f};
  f32x4 acc_o[2][8] = {};   // [half][nd]: rows d=nd*16+g*4+r, col q

  const char* Kh = (const char*)(Kb + (size_t)h * KVL * HD);
  const char* Vh = (const char*)(Vt + (size_t)h * HD * KVL);

#define STAGE_K(t, b)                                                          \
  {                                                                            \
    _Pragma("unroll") for (int i = 0; i < 4; ++i) {                            \
      int c = wid * 4 + i;                                                     \
      int krow = c * 4 + (lane >> 4);          /* LDS row */                   \
      int kglob = PKV(krow);                   /* permuted global kv row */    \
      int klcb = (16 * (lane & 15)) ^ ((krow & 7) << 4);                       \
      GLOAD_LDS16(Kh + (size_t)((t) * KVT + kglob) * 256 + klcb,               \
                  (char*)Ks[b] + c * 1024);                                    \
    }                                                                          \
  }
#define STAGE_V(t, b)                                                          \
  {                                                                            \
    _Pragma("unroll") for (int i = 0; i < 4; ++i) {                            \
      int c = wid * 4 + i;                                                     \
      int vrow = c * 8 + (lane >> 3);                                          \
      int vlcb = (16 * (lane & 7)) ^ ((vrow & 7) << 4);                        \
      GLOAD_LDS16(Vh + (size_t)vrow * (KVL * 2) + (size_t)(t) * 128 + vlcb,    \
                  (char*)Vs[b] + c * 1024);                                    \
    }                                                                          \
  }

  STAGE_K(kt0, 0);
  STAGE_V(kt0, 0);
  STAGE_K(kt0 + 1, 1);
  STAGE_V(kt0 + 1, 1);
  __syncthreads();   // drains all 4 staging DMAs; tiles 0,1 visible

  for (int kt = 0; kt < NT2; ++kt) {
    const int cur = kt & 1;

    // ---- S^T = K Q^T on tile kt (buf cur) ----
    f32x4 s[2][4];
#pragma unroll
    for (int n = 0; n < 4; ++n) {
      s[0][n] = (f32x4){0.f, 0.f, 0.f, 0.f};
      s[1][n] = (f32x4){0.f, 0.f, 0.f, 0.f};
    }
    __builtin_amdgcn_s_setprio(1);
#pragma unroll
    for (int n = 0; n < 4; ++n) {
      int row = n * 16 + qi;
#pragma unroll
      for (int c = 0; c < 4; ++c) {
        int cb = (c * 32 + g * 8) * 2;
        short8 kf = *reinterpret_cast<const short8*>(
            (const char*)Ks[cur] + row * 256 + (cb ^ ((row & 7) << 4)));
        s[0][n] = __builtin_amdgcn_mfma_f32_16x16x32_bf16(kf, qf[0][c], s[0][n], 0, 0, 0);
        s[1][n] = __builtin_amdgcn_mfma_f32_16x16x32_bf16(kf, qf[1][c], s[1][n], 0, 0, 0);
      }
    }
    __builtin_amdgcn_s_setprio(0);

    // ---- online softmax in log2 domain (defer-max THR=8); l lane-local ----
    float p[2][4][4];
    int okv = 1;
    float tmax[2];
#pragma unroll
    for (int hf = 0; hf < 2; ++hf) {
      float t0 = s[hf][0][0];
#pragma unroll
      for (int n = 0; n < 4; ++n)
#pragma unroll
        for (int r = 0; r < 4; ++r) t0 = fmaxf(t0, s[hf][n][r]);
      t0 = fmaxf(t0, __shfl_xor(t0, 16, 64));
      t0 = fmaxf(t0, __shfl_xor(t0, 32, 64));
      tmax[hf] = t0;
      okv &= (t0 <= m_r[hf] + 8.0f);
    }
    if (!__all(okv)) {
#pragma unroll
      for (int hf = 0; hf < 2; ++hf) {
        float mn = fmaxf(m_r[hf], tmax[hf]);
        float alpha = FEXP2(m_r[hf] - mn);
        l_r[hf] *= alpha;
        m_r[hf] = mn;
#pragma unroll
        for (int nd = 0; nd < 8; ++nd) acc_o[hf][nd] *= alpha;
      }
    }
#pragma unroll
    for (int hf = 0; hf < 2; ++hf) {
      float sum = 0.f;
#pragma unroll
      for (int n = 0; n < 4; ++n)
#pragma unroll
        for (int r = 0; r < 4; ++r) {
          p[hf][n][r] = FEXP2(s[hf][n][r] - m_r[hf]);
          sum += p[hf][n][r];
        }
      l_r[hf] += sum;
    }

    // ---- pack to bf16 pairs; PV fragments = register renames (PKV ordering) ----
    unsigned pr[2][4][2];
#pragma unroll
    for (int hf = 0; hf < 2; ++hf)
#pragma unroll
      for (int n = 0; n < 4; ++n)
#pragma unroll
        for (int rr = 0; rr < 2; ++rr) {
          union { __hip_bfloat162 b; unsigned u; } cv;
          cv.b = __float22bfloat162_rn(make_float2(p[hf][n][2 * rr], p[hf][n][2 * rr + 1]));
          pr[hf][n][rr] = cv.u;
        }
#pragma unroll
    for (int kc = 0; kc < 2; ++kc) {
      short8 pv[2];
#pragma unroll
      for (int hf = 0; hf < 2; ++hf) {
        union { unsigned u[4]; short8 s8; } u;
        u.u[0] = pr[hf][2 * kc][0];
        u.u[1] = pr[hf][2 * kc][1];
        u.u[2] = pr[hf][2 * kc + 1][0];
        u.u[3] = pr[hf][2 * kc + 1][1];
        pv[hf] = u.s8;
      }
      __builtin_amdgcn_s_setprio(1);
#pragma unroll
      for (int nd = 0; nd < 8; ++nd) {
        int row = nd * 16 + qi;
        int cb = kc * 64 + g * 16;
        short8 vf = *reinterpret_cast<const short8*>(
            (const char*)Vs[cur] + row * 128 + (cb ^ ((row & 7) << 4)));
        acc_o[0][nd] = __builtin_amdgcn_mfma_f32_16x16x32_bf16(vf, pv[0], acc_o[0][nd], 0, 0, 0);
        acc_o[1][nd] = __builtin_amdgcn_mfma_f32_16x16x32_bf16(vf, pv[1], acc_o[1][nd], 0, 0, 0);
      }
      __builtin_amdgcn_s_setprio(0);
    }

    __syncthreads();   // all waves done with tile kt; iter kt-1's staged DMAs drained
    if (kt + 2 < NT2) {
      STAGE_K(kt0 + kt + 2, cur);   // buf cur free; lands by next iter's barrier
      STAGE_V(kt0 + kt + 2, cur);
    }
  }

  // cross-quarter l reduction (deferred from the loop)
#pragma unroll
  for (int hf = 0; hf < 2; ++hf) {
    l_r[hf] += __shfl_xor(l_r[hf], 16, 64);
    l_r[hf] += __shfl_xor(l_r[hf], 32, 64);
  }

  float* Op = split ? A1 : A0;
#pragma unroll
  for (int hf = 0; hf < 2; ++hf) {
    float* orow = Op + (size_t)(q0 + hf * 16 + qi) * H_DIM + h * HD;
#pragma unroll
    for (int nd = 0; nd < 8; ++nd)
      *reinterpret_cast<float4*>(orow + nd * 16 + g * 4) =
          *reinterpret_cast<const float4*>(&acc_o[hf][nd]);
    if (g == 0) {
      int q = q0 + hf * 16 + qi;
      Mp[split * (NH * SEQ) + h * SEQ + q] = m_r[hf];
      Lp[split * (NH * SEQ) + h * SEQ + q] = l_r[hf];
    }
  }
#undef STAGE_K
#undef STAGE_V
}

// ---------------- combine the two KV-splits (m in log2 domain) ----------------
__global__ void k_combine(const float* __restrict__ A1, const float* __restrict__ Mp,
                          const float* __restrict__ Lp, float* __restrict__ out) {
  int i4 = blockIdx.x * 256 + threadIdx.x;  // < SEQ*H_DIM/4
  int q = i4 >> 10;                          // H_DIM/4 = 1024 float4 per row
  int c4 = i4 & 1023;
  int h = c4 >> 5;                           // 32 float4 per head
  float m0 = Mp[h * SEQ + q], m1 = Mp[NH * SEQ + h * SEQ + q];
  float l0 = Lp[h * SEQ + q], l1 = Lp[NH * SEQ + h * SEQ + q];
  float M = fmaxf(m0, m1);
  float w0 = FEXP2(m0 - M), w1 = FEXP2(m1 - M);
  float inv = 1.0f / (w0 * l0 + w1 * l1);
  float4 a0 = reinterpret_cast<const float4*>(out)[i4];
  float4 a1 = reinterpret_cast<const float4*>(A1)[i4];
  float4 o;
  o.x = (w0 * a0.x + w1 * a1.x) * inv;
  o.y = (w0 * a0.y + w1 * a1.y) * inv;
  o.z = (w0 * a0.z + w1 * a1.z) * inv;
  o.w = (w0 * a0.w + w1 * a1.w) * inv;
  reinterpret_cast<float4*>(out)[i4] = o;
}

extern "C" void kernel_launch(void* const* d_in, const int* in_sizes, int n_in,
                              void* d_out, int out_size, void* d_ws, size_t ws_size,
                              hipStream_t stream) {
  const float* X = (const float*)d_in[0];
  const float* W = (const float*)d_in[1];
  const float* cK = (const float*)d_in[2];
  const float* cV = (const float*)d_in[3];
  float* out = (float*)d_out;
  char* ws = (char*)d_ws;

  // ws: Xb[0,8M) QKVb[8M,32M) Wb/Kb[32M,72M) Vt[72M,112M) A1[112M,128M)
  // Mp/Lp alias Xb's first 512K — Xb is dead after the GEMM, k_attn runs after it,
  // and k_cvt2 fully rewrites Xb every call => deterministic across replays.
  unsigned short* Xb = (unsigned short*)(ws);
  float* Mp = (float*)(ws);
  float* Lp = (float*)(ws + (256 << 10));
  unsigned short* QKVb = (unsigned short*)(ws + ((size_t)8 << 20));
  unsigned short* Wb = (unsigned short*)(ws + ((size_t)32 << 20));
  unsigned short* Kb = (unsigned short*)(ws + ((size_t)32 << 20));
  unsigned short* Vt = (unsigned short*)(ws + ((size_t)72 << 20));
  float* A1 = (float*)(ws + ((size_t)112 << 20));

  int ncvt = (SEQ * H_DIM + W3H * H_DIM) / 4;
  k_cvt2<<<(ncvt + 255) / 256, 256, 0, stream>>>(X, W, Xb, Wb);

  k_gemm_qkv<<<(SEQ / GBM) * (W3H / GBN), 512, 0, stream>>>(Xb, Wb, QKVb);

  k_build_k<<<(NH * KVL * HD / 4) / 256, 256, 0, stream>>>(cK, QKVb, Kb);
  dim3 gv(KVL / 64, NH);
  k_build_vt<<<gv, 256, 0, stream>>>(cV, QKVb, Vt);

  k_attn<<<SEQ / 128 * NH * 2, 256, 0, stream>>>(QKVb, Kb, Vt, out, A1, Mp, Lp);
  k_combine<<<(SEQ * H_DIM / 4) / 256, 256, 0, stream>>>(A1, Mp, Lp, out);
}